// Round 2
// baseline (280.719 us; speedup 1.0000x reference)
//
#include <hip/hip_runtime.h>

#define EPSL 1e-9f
#define NGROUPS 638976              // 8192 * 26 * 3 groups of 31
#define GPB 256                     // groups per block (1 per thread)
#define TILE (GPB * 31)             // 7936 floats per tensor per block
#define NBLOCKS (NGROUPS / GPB)     // 2496 exactly (no remainder)

__global__ __launch_bounds__(256, 2) void laneline_fused_kernel(
    const float* __restrict__ pred,
    const float* __restrict__ gt,
    float* __restrict__ ws,         // ws[0..2] = partial sums, ws[3] = done counter
    float* __restrict__ out)
{
    __shared__ float sp[TILE];      // 31744 B
    __shared__ float sg[TILE];      // 31744 B
    __shared__ float red[12];

    // ---- stage: coalesced float4 global -> LDS ----
    const long long blockStart = (long long)blockIdx.x * TILE;
    const float4* __restrict__ p4 = reinterpret_cast<const float4*>(pred + blockStart);
    const float4* __restrict__ g4 = reinterpret_cast<const float4*>(gt + blockStart);
    float4* sp4 = reinterpret_cast<float4*>(sp);
    float4* sg4 = reinterpret_cast<float4*>(sg);
    for (int i = threadIdx.x; i < TILE / 4; i += 256) {
        sp4[i] = p4[i];
        sg4[i] = g4[i];
    }
    __syncthreads();

    // ---- compute: one full 31-dim group per thread, no divergence ----
    // LDS stride 31 (odd): lane t, dim d hits bank (31t+d)%32 -> exactly 2
    // lanes/bank across a wave64 = free (m136).
    const float* lp = sp + threadIdx.x * 31;
    const float* lg = sg + threadIdx.x * 31;

    const float gcls = lg[30];
    float s0 = 0.f, s2 = 0.f;
#pragma unroll
    for (int i = 0; i < 10; ++i) {
        const float gvis = lg[20 + i];
        const float w = gcls * gvis;
        s2 += fabsf(w * (lp[i]      - lg[i]))
            + fabsf(w * (lp[10 + i] - lg[10 + i]));
        const float pv = lp[20 + i];
        s0 += gvis * __logf(pv + EPSL)
            + (1.0f - gvis + EPSL) * __logf(1.0f - pv + EPSL);
    }
    const float pc = lp[30];
    const float s1 = gcls * __logf(pc + EPSL)
                   + (1.0f - gcls) * __logf(1.0f - pc + EPSL);

    // ---- wave(64) shuffle reduction ----
    float r0 = s0, r1 = s1, r2 = s2;
#pragma unroll
    for (int off = 32; off > 0; off >>= 1) {
        r0 += __shfl_down(r0, off, 64);
        r1 += __shfl_down(r1, off, 64);
        r2 += __shfl_down(r2, off, 64);
    }
    const int lane = threadIdx.x & 63;
    const int wid  = threadIdx.x >> 6;
    if (lane == 0) { red[wid] = r0; red[4 + wid] = r1; red[8 + wid] = r2; }
    __syncthreads();

    if (threadIdx.x == 0) {
        const float t0 = red[0] + red[1] + red[2]  + red[3];
        const float t1 = red[4] + red[5] + red[6]  + red[7];
        const float t2 = red[8] + red[9] + red[10] + red[11];
        atomicAdd(&ws[0], t0);
        atomicAdd(&ws[1], t1);
        atomicAdd(&ws[2], t2);
        __threadfence();
        const unsigned prev = atomicAdd(reinterpret_cast<unsigned*>(ws + 3), 1u);
        if (prev == NBLOCKS - 1) {
            // last block: all other blocks' adds are fenced-before their
            // counter increment; read via device-scope atomics.
            const float v0 = atomicAdd(&ws[0], 0.0f);
            const float v1 = atomicAdd(&ws[1], 0.0f);
            const float v2 = atomicAdd(&ws[2], 0.0f);
            const float l0 = -v0 * 0.1f;   // / NUM_Y_STEPS, negated
            const float l1 = -v1;
            const float l2 =  v2;
            out[0] = l0 + l1 + l2;
            out[1] = l0;
            out[2] = l1;
            out[3] = l2;
        }
    }
}

extern "C" void kernel_launch(void* const* d_in, const int* in_sizes, int n_in,
                              void* d_out, int out_size, void* d_ws, size_t ws_size,
                              hipStream_t stream)
{
    const float* pred = (const float*)d_in[0];
    const float* gt   = (const float*)d_in[1];
    // d_in[2..5] (hcam/pitch) are unused by the reference computation.
    float* ws  = (float*)d_ws;
    float* out = (float*)d_out;

    hipMemsetAsync(ws, 0, 4 * sizeof(float), stream);  // sums + done counter

    laneline_fused_kernel<<<NBLOCKS, 256, 0, stream>>>(pred, gt, ws, out);
}